// Round 1
// baseline (843.816 us; speedup 1.0000x reference)
//
#include <hip/hip_runtime.h>
#include <hip/hip_bf16.h>

#define IN_F 4096
#define OUT_F 4096
#define CPN 81
#define OINV 2225   // 81^{-1} mod 4096  (81*2225 = 180225 = 44*4096 + 1)

#define BM 64       // batch rows per block
#define GPB 16      // groups of 16 outputs per block -> 256 outputs/block
#define LDSTR 344   // LDS row stride in bf16 elems (16B aligned, good bank spread)

typedef __attribute__((ext_vector_type(4))) float f32x4;
typedef __attribute__((ext_vector_type(8))) short bf16x8;

__device__ __forceinline__ unsigned short f2bf(float f) {
  __hip_bfloat16 h = __float2bfloat16(f);
  return *reinterpret_cast<unsigned short*>(&h);
}

// Pack weight*mask into MFMA B-fragment order:
// wfrag[g][t][lane][i], g=0..255 (16 outputs each), t=0..2 (K step of 32),
// lane: n = lane&15 (output col), kg = lane>>4; element i -> k = 32t+8kg+i.
// Group g covers band-start s = 16g+n, output o = (2225*s) & 4095,
// tile col c = k corresponds to global col (16g+c) & 4095; nonzero iff 0 <= c-n < 81.
__global__ void prep_wfrag(const float* __restrict__ w,
                           const float* __restrict__ mask,
                           unsigned short* __restrict__ wfrag) {
  int idx = blockIdx.x * 256 + threadIdx.x;   // one thread per (g,t,lane), 49152 total
  int lane = idx & 63;
  int t = (idx >> 6) % 3;
  int g = idx / 192;
  int n = lane & 15;
  int kg = lane >> 4;
  int s = g * 16 + n;
  int o = (OINV * s) & 4095;
  unsigned short v8[8];
#pragma unroll
  for (int i = 0; i < 8; ++i) {
    int c = 32 * t + 8 * kg + i;
    int j = c - n;                      // connection index within the band
    float v = 0.f;
    if (j >= 0 && j < CPN) {
      int col = (16 * g + c) & 4095;
      v = w[(size_t)o * IN_F + col] * mask[(size_t)o * IN_F + col];
    }
    v8[i] = f2bf(v);
  }
  *reinterpret_cast<bf16x8*>(wfrag + (size_t)idx * 8) =
      *reinterpret_cast<const bf16x8*>(v8);
}

// Main: block = 64 batch rows x 16 groups (256 permuted outputs).
// Stage x[64][336] fp32->bf16 in LDS, then 4 waves x (16 groups x 3 MFMA).
__global__ __launch_bounds__(256, 3) void sc_main(
    const float* __restrict__ x, const float* __restrict__ bias,
    const unsigned short* __restrict__ wfrag, float* __restrict__ out) {
  const int bstrip = blockIdx.x;   // 0..255  (fast dim -> all gb of a strip on one XCD)
  const int gb = blockIdx.y;       // 0..15
  const int b0 = bstrip * BM;
  const int S0 = gb * 256;         // first band-start covered by this block

  __shared__ unsigned short xl[BM * LDSTR];   // 44032 B

  const int tid = threadIdx.x;

  // ---- stage: 64 rows x 84 float4 (336 cols), convert to bf16 ----
#pragma unroll
  for (int k = 0; k < (BM * 84) / 256; ++k) {   // 21 iters
    int idx = tid + k * 256;
    int row = idx / 84;
    int c4 = idx - row * 84;
    int col = (S0 + 4 * c4) & 4095;             // 4-aligned, never straddles wrap
    const float4 v = *reinterpret_cast<const float4*>(
        x + (size_t)(b0 + row) * IN_F + col);
    ushort4 h;
    h.x = f2bf(v.x); h.y = f2bf(v.y); h.z = f2bf(v.z); h.w = f2bf(v.w);
    *reinterpret_cast<ushort4*>(xl + row * LDSTR + 4 * c4) = h;
  }
  __syncthreads();

  const int wave = tid >> 6;       // 0..3 -> batch rows [16w, 16w+16)
  const int lane = tid & 63;
  const int ln = lane & 15;        // A: row / B: col / D: col
  const int lk = lane >> 4;        // k-group

  f32x4 acc[GPB];
#pragma unroll
  for (int g = 0; g < GPB; ++g) acc[g] = f32x4{0.f, 0.f, 0.f, 0.f};

  const bf16x8* wf = reinterpret_cast<const bf16x8*>(wfrag)
                   + (size_t)gb * GPB * 3 * 64 + lane;
  const unsigned short* arow = xl + (16 * wave + ln) * LDSTR + 8 * lk;

#pragma unroll
  for (int g = 0; g < GPB; ++g) {
#pragma unroll
    for (int t = 0; t < 3; ++t) {
      bf16x8 a = *reinterpret_cast<const bf16x8*>(arow + 16 * g + 32 * t);
      bf16x8 b = wf[(g * 3 + t) * 64];
      acc[g] = __builtin_amdgcn_mfma_f32_16x16x32_bf16(a, b, acc[g], 0, 0, 0);
    }
  }

  // ---- epilogue: D row = 4*lk + r (batch), D col = ln (output) ----
  const int row0 = b0 + 16 * wave + 4 * lk;
#pragma unroll
  for (int g = 0; g < GPB; ++g) {
    int s = S0 + 16 * g + ln;
    int o = (OINV * s) & 4095;
    float bs = bias[o];
#pragma unroll
    for (int r = 0; r < 4; ++r)
      out[(size_t)(row0 + r) * OUT_F + o] = acc[g][r] + bs;
  }
}

extern "C" void kernel_launch(void* const* d_in, const int* in_sizes, int n_in,
                              void* d_out, int out_size, void* d_ws, size_t ws_size,
                              hipStream_t stream) {
  const float* x    = (const float*)d_in[0];
  const float* w    = (const float*)d_in[1];
  const float* bias = (const float*)d_in[2];
  const float* mask = (const float*)d_in[3];
  float* out = (float*)d_out;
  unsigned short* wfrag = (unsigned short*)d_ws;   // needs 786432 B

  const int B = in_sizes[0] / IN_F;                // 16384

  prep_wfrag<<<192, 256, 0, stream>>>(w, mask, wfrag);

  dim3 grid(B / BM, OUT_F / (16 * GPB));           // (256, 16)
  sc_main<<<grid, 256, 0, stream>>>(x, bias, wfrag, out);
}

// Round 2
// 239.807 us; speedup vs baseline: 3.5187x; 3.5187x over previous
//
#include <hip/hip_runtime.h>
#include <hip/hip_bf16.h>

#define IN_F 4096
#define OUT_F 4096
#define CPN 81
#define OINV 2225   // 81^{-1} mod 4096
#define BATCH 16384

#define BM 64       // batch rows per block (pass 1)
#define GPB 16      // groups of 16 outputs per block -> 256 outputs/block
#define LDSTR 344   // LDS row stride in bf16 elems

typedef __attribute__((ext_vector_type(4))) float f32x4;
typedef __attribute__((ext_vector_type(8))) short bf16x8;
typedef __attribute__((ext_vector_type(8))) unsigned short u16x8;

__device__ __forceinline__ unsigned short f2bf(float f) {
  __hip_bfloat16 h = __float2bfloat16(f);
  return *reinterpret_cast<unsigned short*>(&h);
}
__device__ __forceinline__ float bf2f(unsigned short u) {
  unsigned int v = ((unsigned int)u) << 16;
  return *reinterpret_cast<float*>(&v);
}

// ---- prep: pack weight*mask into MFMA B-fragment order (unchanged) ----
__global__ void prep_wfrag(const float* __restrict__ w,
                           const float* __restrict__ mask,
                           unsigned short* __restrict__ wfrag) {
  int idx = blockIdx.x * 256 + threadIdx.x;   // 49152 threads: (g,t,lane)
  int lane = idx & 63;
  int t = (idx >> 6) % 3;
  int g = idx / 192;
  int n = lane & 15;
  int kg = lane >> 4;
  int s = g * 16 + n;
  int o = (OINV * s) & 4095;
  unsigned short v8[8];
#pragma unroll
  for (int i = 0; i < 8; ++i) {
    int c = 32 * t + 8 * kg + i;
    int j = c - n;
    float v = 0.f;
    if (j >= 0 && j < CPN) {
      int col = (16 * g + c) & 4095;
      v = w[(size_t)o * IN_F + col] * mask[(size_t)o * IN_F + col];
    }
    v8[i] = f2bf(v);
  }
  *reinterpret_cast<bf16x8*>(wfrag + (size_t)idx * 8) =
      *reinterpret_cast<const bf16x8*>(v8);
}

// ---- pass 1: MFMA over dense permuted bands ----
// TOWS=true : write ws_t[s][row] bf16 (coalesced), bias deferred to pass 2.
// TOWS=false: legacy direct scattered write (fallback if ws too small).
template <bool TOWS>
__global__ __launch_bounds__(256, 3) void sc_main(
    const float* __restrict__ x, const float* __restrict__ bias,
    const unsigned short* __restrict__ wfrag, void* __restrict__ outp) {
  const int bstrip = blockIdx.x;   // 0..255
  const int gb = blockIdx.y;       // 0..15
  const int b0 = bstrip * BM;
  const int S0 = gb * 256;

  __shared__ unsigned short xl[BM * LDSTR];

  const int tid = threadIdx.x;

  // stage x[64][336] fp32 -> bf16
#pragma unroll
  for (int k = 0; k < (BM * 84) / 256; ++k) {   // 21 iters
    int idx = tid + k * 256;
    int row = idx / 84;
    int c4 = idx - row * 84;
    int col = (S0 + 4 * c4) & 4095;
    const float4 v = *reinterpret_cast<const float4*>(
        x + (size_t)(b0 + row) * IN_F + col);
    ushort4 h;
    h.x = f2bf(v.x); h.y = f2bf(v.y); h.z = f2bf(v.z); h.w = f2bf(v.w);
    *reinterpret_cast<ushort4*>(xl + row * LDSTR + 4 * c4) = h;
  }
  __syncthreads();

  const int wave = tid >> 6;
  const int lane = tid & 63;
  const int ln = lane & 15;
  const int lk = lane >> 4;

  f32x4 acc[GPB];
#pragma unroll
  for (int g = 0; g < GPB; ++g) acc[g] = f32x4{0.f, 0.f, 0.f, 0.f};

  const bf16x8* wf = reinterpret_cast<const bf16x8*>(wfrag)
                   + (size_t)gb * GPB * 3 * 64 + lane;
  const unsigned short* arow = xl + (16 * wave + ln) * LDSTR + 8 * lk;

#pragma unroll
  for (int g = 0; g < GPB; ++g) {
#pragma unroll
    for (int t = 0; t < 3; ++t) {
      bf16x8 a = *reinterpret_cast<const bf16x8*>(arow + 16 * g + 32 * t);
      bf16x8 b = wf[(g * 3 + t) * 64];
      acc[g] = __builtin_amdgcn_mfma_f32_16x16x32_bf16(a, b, acc[g], 0, 0, 0);
    }
  }

  const int row0 = b0 + 16 * wave + 4 * lk;   // D rows = 4*lk + r
  if (TOWS) {
    unsigned short* ws = reinterpret_cast<unsigned short*>(outp);
#pragma unroll
    for (int g = 0; g < GPB; ++g) {
      int s = S0 + 16 * g + ln;
      ushort4 h;
      h.x = f2bf(acc[g][0]); h.y = f2bf(acc[g][1]);
      h.z = f2bf(acc[g][2]); h.w = f2bf(acc[g][3]);
      *reinterpret_cast<ushort4*>(ws + (size_t)s * BATCH + row0) = h;
    }
  } else {
    float* out = reinterpret_cast<float*>(outp);
#pragma unroll
    for (int g = 0; g < GPB; ++g) {
      int s = S0 + 16 * g + ln;
      int o = (OINV * s) & 4095;
      float bs = bias[o];
#pragma unroll
      for (int r = 0; r < 4; ++r)
        out[(size_t)(row0 + r) * OUT_F + o] = acc[g][r] + bs;
    }
  }
}

// ---- pass 2: permute ws_t[s][row] -> out[row][o] + bias, via LDS tile ----
// block: 64 outputs x 128 rows; reads 256B segments, writes 256B row chunks.
__global__ __launch_bounds__(256) void sc_perm(
    const unsigned short* __restrict__ ws, const float* __restrict__ bias,
    float* __restrict__ out) {
  const int r0 = blockIdx.x * 128;   // row tile (fast dim)
  const int o0 = blockIdx.y * 64;    // output tile

  __shared__ float t[64 * 129];      // [o_local][row_local], stride 129

  const int tid = threadIdx.x;

  // load: 64 o x 128 rows bf16 = 1024 x 16B reads
#pragma unroll
  for (int i = 0; i < 4; ++i) {
    int idx = tid + 256 * i;
    int ol = idx >> 4;          // 0..63
    int seg = idx & 15;         // 8-row segment
    int s = (CPN * (o0 + ol)) & 4095;
    u16x8 v = *reinterpret_cast<const u16x8*>(
        ws + (size_t)s * BATCH + r0 + 8 * seg);
#pragma unroll
    for (int j = 0; j < 8; ++j) t[ol * 129 + 8 * seg + j] = bf2f(v[j]);
  }
  __syncthreads();

  const int wave = tid >> 6;
  const int lane = tid & 63;
  const int o4 = lane & 15;     // 4-output chunk
  const int ro = lane >> 4;     // row offset within wave

  const float4 b4 = *reinterpret_cast<const float4*>(bias + o0 + 4 * o4);

#pragma unroll
  for (int i = 0; i < 8; ++i) {
    int row_l = 16 * i + 4 * wave + ro;   // 0..127
    float4 res;
    res.x = t[(4 * o4 + 0) * 129 + row_l] + b4.x;
    res.y = t[(4 * o4 + 1) * 129 + row_l] + b4.y;
    res.z = t[(4 * o4 + 2) * 129 + row_l] + b4.z;
    res.w = t[(4 * o4 + 3) * 129 + row_l] + b4.w;
    *reinterpret_cast<float4*>(out + (size_t)(r0 + row_l) * OUT_F + o0 + 4 * o4) = res;
  }
}

extern "C" void kernel_launch(void* const* d_in, const int* in_sizes, int n_in,
                              void* d_out, int out_size, void* d_ws, size_t ws_size,
                              hipStream_t stream) {
  const float* x    = (const float*)d_in[0];
  const float* w    = (const float*)d_in[1];
  const float* bias = (const float*)d_in[2];
  const float* mask = (const float*)d_in[3];
  float* out = (float*)d_out;

  unsigned short* wfrag = (unsigned short*)d_ws;            // 786432 B
  const size_t WS_OFF = 1u << 20;                            // 1 MB align
  const size_t need = WS_OFF + (size_t)OUT_F * BATCH * 2;    // + 128 MB
  unsigned short* ws_t = (unsigned short*)((char*)d_ws + WS_OFF);

  prep_wfrag<<<192, 256, 0, stream>>>(w, mask, wfrag);

  dim3 grid1(BATCH / BM, OUT_F / (16 * GPB));                // (256, 16)
  if (ws_size >= need) {
    sc_main<true><<<grid1, 256, 0, stream>>>(x, bias, wfrag, (void*)ws_t);
    dim3 grid2(BATCH / 128, OUT_F / 64);                     // (128, 64)
    sc_perm<<<grid2, 256, 0, stream>>>(ws_t, bias, out);
  } else {
    sc_main<false><<<grid1, 256, 0, stream>>>(x, bias, wfrag, (void*)out);
  }
}